// Round 1
// baseline (1141.141 us; speedup 1.0000x reference)
//
#include <hip/hip_runtime.h>

#define N 128
#define LSAP_INF 1e30f

// One wave (64 lanes) per batch. Lane L owns columns {L, L+64} and rows
// {L, L+64}. All solver state lives in registers; cross-lane data movement is
// via __shfl (wave64 lockstep -> no barriers needed in the hot loop).
// The 128x128 fp32 cost matrix (64 KB) is staged into LDS once.
__global__ __launch_bounds__(64) void lsap_kernel(const float* __restrict__ D,
                                                  float* __restrict__ batch_sums) {
    const int b = blockIdx.x;
    const int lane = threadIdx.x;  // 0..63
    const float* __restrict__ C = D + (size_t)b * N * N;

    __shared__ float Cs[N * N];  // 65536 bytes

    // Stage C -> LDS, coalesced float4 loads.
    {
        const float4* __restrict__ src = (const float4*)C;
        float4* dst = (float4*)Cs;
#pragma unroll
        for (int t = 0; t < (N * N / 4) / 64; ++t) {
            dst[t * 64 + lane] = src[t * 64 + lane];
        }
    }
    __syncthreads();  // single wave: just drains LDS writes

    // Column-owned state (col j0 = lane, j1 = lane+64)
    float v0 = 0.f, v1 = 0.f;      // dual v
    int r4c0 = -1, r4c1 = -1;      // row4col
    // Row-owned state (row r0 = lane, r1 = lane+64)
    float u0 = 0.f, u1 = 0.f;      // dual u
    int c4r0 = -1, c4r1 = -1;      // col4row

    for (int cur = 0; cur < N; ++cur) {
        // Per-augment scratch
        float spc0 = LSAP_INF, spc1 = LSAP_INF;  // shortestPathCosts
        int path0 = -1, path1 = -1;
        bool rem0 = true, rem1 = true;   // remaining
        bool sc0 = false, sc1 = false;   // SC
        bool sr0 = false, sr1 = false;   // SR
        int i = cur;
        float minVal = 0.f;
        int sink = -1;

        while (sink < 0) {
            // SR.add(i)
            sr0 = sr0 | (i == lane);
            sr1 = sr1 | (i == lane + 64);
            // u[i] broadcast (i is wave-uniform)
            float ui_src = (i < 64) ? u0 : u1;
            float u_i = __shfl(ui_src, i & 63);
            // Row i of C from LDS
            float c0 = Cs[i * N + lane];
            float c1 = Cs[i * N + lane + 64];
            float base = minVal - u_i;
            float r0 = base + c0 - v0;
            float r1 = base + c1 - v1;
            if (rem0 && (r0 < spc0)) { spc0 = r0; path0 = i; }
            if (rem1 && (r1 < spc1)) { spc1 = r1; path1 = i; }
            // argmin over remaining (lowest-index tie-break, like jnp.argmin)
            float m0 = rem0 ? spc0 : LSAP_INF;
            float m1 = rem1 ? spc1 : LSAP_INF;
            float mv;
            int mj;
            if (m1 < m0) { mv = m1; mj = lane + 64; }
            else         { mv = m0; mj = lane; }
#pragma unroll
            for (int off = 32; off >= 1; off >>= 1) {
                float ov = __shfl_xor(mv, off);
                int oj = __shfl_xor(mj, off);
                if (ov < mv || (ov == mv && oj < mj)) { mv = ov; mj = oj; }
            }
            minVal = mv;
            int j = mj;  // wave-uniform
            // row4col[j]
            int rj_src = (j < 64) ? r4c0 : r4c1;
            int rj = __shfl(rj_src, j & 63);
            // SC.add(j); remaining.remove(j)
            if (lane == (j & 63)) {
                if (j < 64) { sc0 = true; rem0 = false; }
                else        { sc1 = true; rem1 = false; }
            }
            if (rj < 0) sink = j;
            else        i = rj;
        }

        // Dual updates.
        {
            // gather spc[col4row[row]] for this lane's two rows
            int g0i = (c4r0 < 0) ? 0 : c4r0;
            int g1i = (c4r1 < 0) ? 0 : c4r1;
            float a0 = __shfl(spc0, g0i & 63);
            float b0 = __shfl(spc1, g0i & 63);
            float g0 = (g0i < 64) ? a0 : b0;
            float a1 = __shfl(spc0, g1i & 63);
            float b1 = __shfl(spc1, g1i & 63);
            float g1 = (g1i < 64) ? a1 : b1;

            if (cur == lane)           u0 += minVal;
            else if (sr0)              u0 += minVal - g0;
            if (cur == lane + 64)      u1 += minVal;
            else if (sr1)              u1 += minVal - g1;
            if (sc0) v0 -= minVal - spc0;
            if (sc1) v1 -= minVal - spc1;
        }

        // Augment along alternating path back to cur.
        int j = sink;
        while (true) {
            int p_src = (j < 64) ? path0 : path1;
            int ip = __shfl(p_src, j & 63);  // wave-uniform
            if (lane == (j & 63)) {
                if (j < 64) r4c0 = ip; else r4c1 = ip;
            }
            int c_src = (ip < 64) ? c4r0 : c4r1;
            int jn = __shfl(c_src, ip & 63);
            if (lane == (ip & 63)) {
                if (ip < 64) c4r0 = j; else c4r1 = j;
            }
            j = jn;
            if (ip == cur) break;
        }
    }

    // Matched sum over this batch: sum_i C[i][col4row[i]]
    float s = Cs[lane * N + c4r0] + Cs[(lane + 64) * N + c4r1];
#pragma unroll
    for (int off = 32; off >= 1; off >>= 1) s += __shfl_xor(s, off);
    if (lane == 0) batch_sums[b] = s;
}

__global__ __launch_bounds__(64) void reduce_kernel(const float* __restrict__ sums,
                                                    float* __restrict__ out,
                                                    int B, float inv) {
    float s = 0.f;
    for (int t = threadIdx.x; t < B; t += 64) s += sums[t];
#pragma unroll
    for (int off = 32; off >= 1; off >>= 1) s += __shfl_xor(s, off);
    if (threadIdx.x == 0) out[0] = s * inv;
}

extern "C" void kernel_launch(void* const* d_in, const int* in_sizes, int n_in,
                              void* d_out, int out_size, void* d_ws, size_t ws_size,
                              hipStream_t stream) {
    const float* D = (const float*)d_in[0];
    float* out = (float*)d_out;
    float* sums = (float*)d_ws;  // B floats of scratch
    const int B = in_sizes[0] / (N * N);
    lsap_kernel<<<B, 64, 0, stream>>>(D, sums);
    reduce_kernel<<<1, 64, 0, stream>>>(sums, out, B, 1.0f / (float)(B * N));
}

// Round 2
// 490.004 us; speedup vs baseline: 2.3288x; 2.3288x over previous
//
#include <hip/hip_runtime.h>

#define N 128
#define LSAP_INF 1e30f

// Uniform-lane readlane helpers (v_readlane_b32 with SGPR index; much cheaper
// than ds_bpermute for wave-uniform indices).
__device__ __forceinline__ int rl_i(int v, int l) { return __builtin_amdgcn_readlane(v, l); }
__device__ __forceinline__ float rl_f(float v, int l) {
    return __int_as_float(__builtin_amdgcn_readlane(__float_as_int(v), l));
}
// Pick from the two 64-wide register slots by global index (0..127), uniform.
__device__ __forceinline__ int pick_i(int a0, int a1, int idx) {
    return (idx < 64) ? rl_i(a0, idx) : rl_i(a1, idx - 64);
}
__device__ __forceinline__ float pick_f(float a0, float a1, int idx) {
    return (idx < 64) ? rl_f(a0, idx) : rl_f(a1, idx - 64);
}

// Full wave64 min via DPP (VALU-only; no LDS latency). Result broadcast via
// readlane 63. Invalid source lanes contribute +INF through `old`.
__device__ __forceinline__ float wave_min_f32(float x) {
    const int infb = __float_as_int(LSAP_INF);
#define DPP_STEP(ctrl)                                                                   \
    x = fminf(x, __int_as_float(__builtin_amdgcn_update_dpp(                             \
               infb, __float_as_int(x), (ctrl), 0xF, 0xF, false)));
    DPP_STEP(0x111)  // row_shr:1
    DPP_STEP(0x112)  // row_shr:2
    DPP_STEP(0x114)  // row_shr:4
    DPP_STEP(0x118)  // row_shr:8
    DPP_STEP(0x142)  // row_bcast:15
    DPP_STEP(0x143)  // row_bcast:31
#undef DPP_STEP
    return rl_f(x, 63);
}

// One wave per batch. Lane L owns columns {L, L+64} and rows {L, L+64}.
// All solver state in registers; cross-lane traffic in the hot loop is
// DPP + readlane + ballot only. C (64 KB) staged in LDS.
__global__ __launch_bounds__(64) void lsap_kernel(const float* __restrict__ D,
                                                  float* __restrict__ batch_sums) {
    const int b = blockIdx.x;
    const int lane = threadIdx.x;  // 0..63
    const float* __restrict__ C = D + (size_t)b * N * N;

    __shared__ float Cs[N * N];   // 65536 B
    __shared__ int claim[N];

    {
        const float4* __restrict__ src = (const float4*)C;
        float4* dst = (float4*)Cs;
#pragma unroll
        for (int t = 0; t < (N * N / 4) / 64; ++t) dst[t * 64 + lane] = src[t * 64 + lane];
    }
    __syncthreads();

    // ---- Column reduction: v[j] = min_i C[i][j], track argmin row ----
    float v0 = LSAP_INF, v1 = LSAP_INF;
    int am0 = -1, am1 = -1;
    for (int i = 0; i < N; ++i) {
        float c0 = Cs[i * N + lane];
        float c1 = Cs[i * N + lane + 64];
        if (c0 < v0) { v0 = c0; am0 = i; }
        if (c1 < v1) { v1 = c1; am1 = i; }
    }

    // ---- Greedy claims: column j claims its argmin row; LDS write race picks
    // an arbitrary (valid) winner. u stays 0, so reduced costs stay >= 0. ----
    claim[lane] = -1;
    claim[lane + 64] = -1;
    __syncthreads();
    claim[am0] = lane;
    claim[am1] = lane + 64;
    __syncthreads();
    int c4r0 = claim[lane];       // col assigned to row `lane` (-1 if none)
    int c4r1 = claim[lane + 64];
    int w0 = claim[am0];
    int w1 = claim[am1];
    int r4c0 = (w0 == lane) ? am0 : -1;       // row assigned to col `lane`
    int r4c1 = (w1 == lane + 64) ? am1 : -1;  // row assigned to col `lane+64`

    float u0 = 0.f, u1 = 0.f;

    for (int cur = 0; cur < N; ++cur) {
        if (pick_i(c4r0, c4r1, cur) >= 0) continue;  // already assigned (uniform)

        // Per-augment scratch
        float spc0 = LSAP_INF, spc1 = LSAP_INF;
        int path0 = -1, path1 = -1;
        bool rem0 = true, rem1 = true;
        bool sc0 = false, sc1 = false;
        bool sr0 = false, sr1 = false;
        int i = cur;                      // uniform
        float u_i = pick_f(u0, u1, i);
        float minVal = 0.f;
        int sink;

        while (true) {
            // SR.add(i)
            if (lane == (i & 63)) { if (i < 64) sr0 = true; else sr1 = true; }
            // Row i of C (ds_read2_b32, conflict-free 2-way)
            float c0 = Cs[i * N + lane];
            float c1 = Cs[i * N + lane + 64];
            float base = minVal - u_i;
            float r0 = base + c0 - v0;
            float r1 = base + c1 - v1;
            if (rem0 && (r0 < spc0)) { spc0 = r0; path0 = i; }
            if (rem1 && (r1 < spc1)) { spc1 = r1; path1 = i; }
            float m0c = rem0 ? spc0 : LSAP_INF;
            float m1c = rem1 ? spc1 : LSAP_INF;
            // Wave-wide argmin: DPP value-min, then ballot to recover index.
            float mv = wave_min_f32(fminf(m0c, m1c));
            unsigned long long b0 = __ballot(m0c == mv);
            int j;
            if (b0) j = __builtin_ctzll(b0);
            else    j = 64 + __builtin_ctzll(__ballot(m1c == mv));
            minVal = mv;
            // row4col[j] via readlane (j uniform)
            int rj = pick_i(r4c0, r4c1, j);
            // SC.add(j); remaining.remove(j)
            if (lane == (j & 63)) {
                if (j < 64) { sc0 = true; rem0 = false; }
                else        { sc1 = true; rem1 = false; }
            }
            if (rj < 0) { sink = j; break; }
            i = rj;
            u_i = pick_f(u0, u1, i);
        }

        // ---- Dual updates ----
        {
            // gather spc[col4row[row]] for this lane's two rows (non-uniform -> shfl)
            int g0i = (c4r0 < 0) ? 0 : c4r0;
            int g1i = (c4r1 < 0) ? 0 : c4r1;
            float a0 = __shfl(spc0, g0i & 63);
            float b0f = __shfl(spc1, g0i & 63);
            float g0 = (g0i < 64) ? a0 : b0f;
            float a1 = __shfl(spc0, g1i & 63);
            float b1f = __shfl(spc1, g1i & 63);
            float g1 = (g1i < 64) ? a1 : b1f;

            if (cur == lane)          u0 += minVal;
            else if (sr0)             u0 += minVal - g0;
            if (cur == lane + 64)     u1 += minVal;
            else if (sr1)             u1 += minVal - g1;
            if (sc0) v0 -= minVal - spc0;
            if (sc1) v1 -= minVal - spc1;
        }

        // ---- Augment along alternating path ----
        int j = sink;
        while (true) {
            int ip = pick_i(path0, path1, j);   // uniform
            if (lane == (j & 63)) { if (j < 64) r4c0 = ip; else r4c1 = ip; }
            int jn = pick_i(c4r0, c4r1, ip);    // read BEFORE overwrite
            if (lane == (ip & 63)) { if (ip < 64) c4r0 = j; else c4r1 = j; }
            if (ip == cur) break;
            j = jn;
        }
    }

    // Matched sum: sum_i C[i][col4row[i]]
    float s = Cs[lane * N + c4r0] + Cs[(lane + 64) * N + c4r1];
#pragma unroll
    for (int off = 32; off >= 1; off >>= 1) s += __shfl_xor(s, off);
    if (lane == 0) batch_sums[b] = s;
}

__global__ __launch_bounds__(64) void reduce_kernel(const float* __restrict__ sums,
                                                    float* __restrict__ out,
                                                    int B, float inv) {
    float s = 0.f;
    for (int t = threadIdx.x; t < B; t += 64) s += sums[t];
#pragma unroll
    for (int off = 32; off >= 1; off >>= 1) s += __shfl_xor(s, off);
    if (threadIdx.x == 0) out[0] = s * inv;
}

extern "C" void kernel_launch(void* const* d_in, const int* in_sizes, int n_in,
                              void* d_out, int out_size, void* d_ws, size_t ws_size,
                              hipStream_t stream) {
    const float* D = (const float*)d_in[0];
    float* out = (float*)d_out;
    float* sums = (float*)d_ws;  // B floats of scratch
    const int B = in_sizes[0] / (N * N);
    lsap_kernel<<<B, 64, 0, stream>>>(D, sums);
    reduce_kernel<<<1, 64, 0, stream>>>(sums, out, B, 1.0f / (float)(B * N));
}

// Round 3
// 380.494 us; speedup vs baseline: 2.9991x; 1.2878x over previous
//
#include <hip/hip_runtime.h>

#define N 128
#define LSAP_INF 1e30f

// Uniform-lane readlane helpers (v_readlane_b32 with SGPR index).
__device__ __forceinline__ int rl_i(int v, int l) { return __builtin_amdgcn_readlane(v, l); }
__device__ __forceinline__ float rl_f(float v, int l) {
    return __int_as_float(__builtin_amdgcn_readlane(__float_as_int(v), l));
}
// Pick from the two 64-wide register slots by global index (0..127), uniform.
__device__ __forceinline__ int pick_i(int a0, int a1, int idx) {
    return (idx < 64) ? rl_i(a0, idx) : rl_i(a1, idx - 64);
}
__device__ __forceinline__ float pick_f(float a0, float a1, int idx) {
    return (idx < 64) ? rl_f(a0, idx) : rl_f(a1, idx - 64);
}

// Full wave64 min via DPP (VALU-only). Result broadcast via readlane 63.
__device__ __forceinline__ float wave_min_f32(float x) {
    const int infb = __float_as_int(LSAP_INF);
#define DPP_STEP(ctrl)                                                                   \
    x = fminf(x, __int_as_float(__builtin_amdgcn_update_dpp(                             \
               infb, __float_as_int(x), (ctrl), 0xF, 0xF, false)));
    DPP_STEP(0x111)  // row_shr:1
    DPP_STEP(0x112)  // row_shr:2
    DPP_STEP(0x114)  // row_shr:4
    DPP_STEP(0x118)  // row_shr:8
    DPP_STEP(0x142)  // row_bcast:15
    DPP_STEP(0x143)  // row_bcast:31
#undef DPP_STEP
    return rl_f(x, 63);
}

// min / argmin / second-min of reduced costs over both lane-owned rows.
// Diagonal scan j=(t+lane)&127: conflict-free (2-way aliasing only).
__device__ __forceinline__ void row_scan2(const float* Cs, const float* v_lds, int lane,
                                          float& m0, int& jm0, float& sm0,
                                          float& m1, int& jm1, float& sm1) {
    m0 = sm0 = m1 = sm1 = LSAP_INF;
    jm0 = jm1 = -1;
    for (int t = 0; t < N; ++t) {
        int j = (t + lane) & (N - 1);
        float vj = v_lds[j];
        float h0 = Cs[lane * N + j] - vj;
        float h1 = Cs[(lane + 64) * N + j] - vj;
        if (h0 < sm0) { if (h0 < m0) { sm0 = m0; m0 = h0; jm0 = j; } else sm0 = h0; }
        if (h1 < sm1) { if (h1 < m1) { sm1 = m1; m1 = h1; jm1 = j; } else sm1 = h1; }
    }
}

// One wave per batch. Lane L owns columns {L, L+64} and rows {L, L+64}.
__global__ __launch_bounds__(64) void lsap_kernel(const float* __restrict__ D,
                                                  float* __restrict__ batch_sums) {
    const int b = blockIdx.x;
    const int lane = threadIdx.x;  // 0..63
    const float* __restrict__ C = D + (size_t)b * N * N;

    __shared__ float Cs[N * N];       // 65536 B
    __shared__ float v_lds[N];
    __shared__ int rowsol_lds[N];     // row -> col (-1 free)
    __shared__ int colsol_lds[N];     // col -> row (-1 free)
    __shared__ int bid_lds[N];

    {
        const float4* __restrict__ src = (const float4*)C;
        float4* dst = (float4*)Cs;
#pragma unroll
        for (int t = 0; t < (N * N / 4) / 64; ++t) dst[t * 64 + lane] = src[t * 64 + lane];
    }
    __syncthreads();

    // ---- JV init phase 1: column reduction v[j] = min_i C[i][j] ----
    {
        float v0 = LSAP_INF, v1 = LSAP_INF;
        int am0 = -1, am1 = -1;
        for (int i = 0; i < N; ++i) {
            float c0 = Cs[i * N + lane];
            float c1 = Cs[i * N + lane + 64];
            if (c0 < v0) { v0 = c0; am0 = i; }
            if (c1 < v1) { v1 = c1; am1 = i; }
        }
        v_lds[lane] = v0;
        v_lds[lane + 64] = v1;
        rowsol_lds[lane] = -1; rowsol_lds[lane + 64] = -1;
        colsol_lds[lane] = -1; colsol_lds[lane + 64] = -1;
        __syncthreads();
        // column j claims its argmin row; LDS write race picks a valid winner
        bid_lds[am0] = lane;
        bid_lds[am1] = lane + 64;
        __syncthreads();
        if (bid_lds[am0] == lane)      { colsol_lds[lane] = am0;      rowsol_lds[am0] = lane; }
        if (bid_lds[am1] == lane + 64) { colsol_lds[lane + 64] = am1; rowsol_lds[am1] = lane + 64; }
        __syncthreads();
    }

    // ---- JV init phase 2: reduction transfer (all assigned rows, parallel) ----
    {
        float m0, sm0, m1, sm1; int jm0, jm1;
        row_scan2(Cs, v_lds, lane, m0, jm0, sm0, m1, jm1, sm1);
        int j1_0 = rowsol_lds[lane];
        int j1_1 = rowsol_lds[lane + 64];
        __syncthreads();
        if (j1_0 >= 0) v_lds[j1_0] -= (sm0 - m0);   // m == 0 here; distinct j1 per row
        if (j1_1 >= 0) v_lds[j1_1] -= (sm1 - m1);
        __syncthreads();
    }

    // ---- JV init phase 3: parallel augmenting-row-reduction (bidding) ----
    for (int round = 0; round < 6; ++round) {
        bool f0 = rowsol_lds[lane] < 0;
        bool f1 = rowsol_lds[lane + 64] < 0;
        if (__ballot(f0 || f1) == 0ULL) break;
        float m0, sm0, m1, sm1; int jm0, jm1;
        row_scan2(Cs, v_lds, lane, m0, jm0, sm0, m1, jm1, sm1);
        bid_lds[lane] = -1;
        bid_lds[lane + 64] = -1;
        __syncthreads();
        if (f0) bid_lds[jm0] = lane;
        if (f1) bid_lds[jm1] = lane + 64;
        __syncthreads();
        if (f0 && bid_lds[jm0] == lane) {            // row `lane` wins column jm0
            int old = colsol_lds[jm0];
            v_lds[jm0] -= (sm0 - m0);
            colsol_lds[jm0] = lane;
            rowsol_lds[lane] = jm0;
            if (old >= 0) rowsol_lds[old] = -1;
        }
        if (f1 && bid_lds[jm1] == lane + 64) {       // row `lane+64` wins column jm1
            int old = colsol_lds[jm1];
            v_lds[jm1] -= (sm1 - m1);
            colsol_lds[jm1] = lane + 64;
            rowsol_lds[lane + 64] = jm1;
            if (old >= 0) rowsol_lds[old] = -1;
        }
        __syncthreads();
    }

    // ---- Load solver state into registers; u[i] = C[i][j1] - v[j1] ----
    float v0 = v_lds[lane], v1 = v_lds[lane + 64];
    int r4c0 = colsol_lds[lane], r4c1 = colsol_lds[lane + 64];
    int c4r0 = rowsol_lds[lane], c4r1 = rowsol_lds[lane + 64];
    float u0 = (c4r0 >= 0) ? (Cs[lane * N + c4r0] - v_lds[c4r0]) : 0.f;
    float u1 = (c4r1 >= 0) ? (Cs[(lane + 64) * N + c4r1] - v_lds[c4r1]) : 0.f;

    // ---- Exact phase: shortest augmenting path for each remaining free row ----
    for (int cur = 0; cur < N; ++cur) {
        if (pick_i(c4r0, c4r1, cur) >= 0) continue;  // already assigned (uniform)

        float spc0 = LSAP_INF, spc1 = LSAP_INF;
        int path0 = -1, path1 = -1;
        bool rem0 = true, rem1 = true;
        bool sc0 = false, sc1 = false;
        bool sr0 = false, sr1 = false;
        int i = cur;                      // uniform
        float u_i = pick_f(u0, u1, i);
        float minVal = 0.f;
        int sink;

        while (true) {
            if (lane == (i & 63)) { if (i < 64) sr0 = true; else sr1 = true; }
            float c0 = Cs[i * N + lane];
            float c1 = Cs[i * N + lane + 64];
            float base = minVal - u_i;
            float r0 = base + c0 - v0;
            float r1 = base + c1 - v1;
            if (rem0 && (r0 < spc0)) { spc0 = r0; path0 = i; }
            if (rem1 && (r1 < spc1)) { spc1 = r1; path1 = i; }
            float m0c = rem0 ? spc0 : LSAP_INF;
            float m1c = rem1 ? spc1 : LSAP_INF;
            float mv = wave_min_f32(fminf(m0c, m1c));
            unsigned long long b0 = __ballot(m0c == mv);
            int j;
            if (b0) j = __builtin_ctzll(b0);
            else    j = 64 + __builtin_ctzll(__ballot(m1c == mv));
            minVal = mv;
            int rj = pick_i(r4c0, r4c1, j);
            if (lane == (j & 63)) {
                if (j < 64) { sc0 = true; rem0 = false; }
                else        { sc1 = true; rem1 = false; }
            }
            if (rj < 0) { sink = j; break; }
            i = rj;
            u_i = pick_f(u0, u1, i);
        }

        // Dual updates
        {
            int g0i = (c4r0 < 0) ? 0 : c4r0;
            int g1i = (c4r1 < 0) ? 0 : c4r1;
            float a0 = __shfl(spc0, g0i & 63);
            float b0f = __shfl(spc1, g0i & 63);
            float g0 = (g0i < 64) ? a0 : b0f;
            float a1 = __shfl(spc0, g1i & 63);
            float b1f = __shfl(spc1, g1i & 63);
            float g1 = (g1i < 64) ? a1 : b1f;

            if (cur == lane)          u0 += minVal;
            else if (sr0)             u0 += minVal - g0;
            if (cur == lane + 64)     u1 += minVal;
            else if (sr1)             u1 += minVal - g1;
            if (sc0) v0 -= minVal - spc0;
            if (sc1) v1 -= minVal - spc1;
        }

        // Augment along alternating path
        int j = sink;
        while (true) {
            int ip = pick_i(path0, path1, j);   // uniform
            if (lane == (j & 63)) { if (j < 64) r4c0 = ip; else r4c1 = ip; }
            int jn = pick_i(c4r0, c4r1, ip);    // read BEFORE overwrite
            if (lane == (ip & 63)) { if (ip < 64) c4r0 = j; else c4r1 = j; }
            if (ip == cur) break;
            j = jn;
        }
    }

    // Matched sum: sum_i C[i][col4row[i]]
    float s = Cs[lane * N + c4r0] + Cs[(lane + 64) * N + c4r1];
#pragma unroll
    for (int off = 32; off >= 1; off >>= 1) s += __shfl_xor(s, off);
    if (lane == 0) batch_sums[b] = s;
}

__global__ __launch_bounds__(64) void reduce_kernel(const float* __restrict__ sums,
                                                    float* __restrict__ out,
                                                    int B, float inv) {
    float s = 0.f;
    for (int t = threadIdx.x; t < B; t += 64) s += sums[t];
#pragma unroll
    for (int off = 32; off >= 1; off >>= 1) s += __shfl_xor(s, off);
    if (threadIdx.x == 0) out[0] = s * inv;
}

extern "C" void kernel_launch(void* const* d_in, const int* in_sizes, int n_in,
                              void* d_out, int out_size, void* d_ws, size_t ws_size,
                              hipStream_t stream) {
    const float* D = (const float*)d_in[0];
    float* out = (float*)d_out;
    float* sums = (float*)d_ws;  // B floats of scratch
    const int B = in_sizes[0] / (N * N);
    lsap_kernel<<<B, 64, 0, stream>>>(D, sums);
    reduce_kernel<<<1, 64, 0, stream>>>(sums, out, B, 1.0f / (float)(B * N));
}